// Round 1
// baseline (1084.411 us; speedup 1.0000x reference)
//
#include <hip/hip_runtime.h>

#define A_COEF (-0.75f)

__device__ __forceinline__ float cc1(float t) {
    return ((A_COEF + 2.0f) * t - (A_COEF + 3.0f)) * t * t + 1.0f;
}
__device__ __forceinline__ float cc2(float t) {
    return ((A_COEF * t - 5.0f * A_COEF) * t + 8.0f * A_COEF) * t - 4.0f * A_COEF;
}

// Re-pack data[c][y][x] (C=4, R x R) -> tex[(y*R+x)*4 + c]  (float4 per texel)
__global__ void interleave_kernel(const float* __restrict__ in, float* __restrict__ out, int RR) {
    int i = blockIdx.x * blockDim.x + threadIdx.x;
    int total = RR * 4;
    if (i >= total) return;
    int c = i & 3;
    int t = i >> 2;
    out[i] = in[c * RR + t];
}

template <bool ILV, int R>
__device__ __forceinline__ void sample_level(const float* __restrict__ base,
                                             float sy, float sx,
                                             float* __restrict__ f) {
    constexpr int RM1 = R - 1;
    float fy = sy * (float)RM1;
    float fx = sx * (float)RM1;
    float y0f = floorf(fy), x0f = floorf(fx);
    float ty = fy - y0f, tx = fx - x0f;
    int y0 = (int)y0f, x0 = (int)x0f;

    float wxa[4] = {cc2(tx + 1.0f), cc1(tx), cc1(1.0f - tx), cc2(2.0f - tx)};
    float wya[4] = {cc2(ty + 1.0f), cc1(ty), cc1(1.0f - ty), cc2(2.0f - ty)};

    int xs[4], ys[4];
#pragma unroll
    for (int j = 0; j < 4; ++j) {
        xs[j] = min(max(x0 - 1 + j, 0), RM1);
        ys[j] = min(max(y0 - 1 + j, 0), RM1);
    }

    if constexpr (ILV) {
        float a0 = 0.f, a1 = 0.f, a2 = 0.f, a3 = 0.f;
#pragma unroll
        for (int i = 0; i < 4; ++i) {
            const float* rowp = base + (size_t)(ys[i] * R) * 4;
            float r0 = 0.f, r1 = 0.f, r2 = 0.f, r3 = 0.f;
#pragma unroll
            for (int j = 0; j < 4; ++j) {
                const float4 v = *reinterpret_cast<const float4*>(rowp + xs[j] * 4);
                r0 = fmaf(wxa[j], v.x, r0);
                r1 = fmaf(wxa[j], v.y, r1);
                r2 = fmaf(wxa[j], v.z, r2);
                r3 = fmaf(wxa[j], v.w, r3);
            }
            a0 = fmaf(wya[i], r0, a0);
            a1 = fmaf(wya[i], r1, a1);
            a2 = fmaf(wya[i], r2, a2);
            a3 = fmaf(wya[i], r3, a3);
        }
        f[0] = a0; f[1] = a1; f[2] = a2; f[3] = a3;
    } else {
#pragma unroll
        for (int c = 0; c < 4; ++c) {
            const float* cp = base + (size_t)c * R * R;
            float ac = 0.f;
#pragma unroll
            for (int i = 0; i < 4; ++i) {
                const float* rowp = cp + (size_t)(ys[i] * R);
                float r = 0.f;
#pragma unroll
                for (int j = 0; j < 4; ++j) r = fmaf(wxa[j], rowp[xs[j]], r);
                ac = fmaf(wya[i], r, ac);
            }
            f[c] = ac;
        }
    }
}

#define LAYER64(IN, OUT, W, B)                                              \
    _Pragma("unroll") for (int j = 0; j < 64; ++j) OUT[j] = (B)[j];         \
    _Pragma("unroll") for (int k = 0; k < 64; ++k) {                        \
        float fk = IN[k];                                                   \
        _Pragma("unroll") for (int j = 0; j < 64; ++j)                      \
            OUT[j] = fmaf(fk, (W)[k * 64 + j], OUT[j]);                     \
    }                                                                       \
    _Pragma("unroll") for (int j = 0; j < 64; ++j) OUT[j] = fmaxf(OUT[j], 0.f);

template <bool ILV>
__global__ __launch_bounds__(256)
void mrv_mlp_kernel(const float* __restrict__ x,
                    const float* __restrict__ d0, const float* __restrict__ d1,
                    const float* __restrict__ d2, const float* __restrict__ d3,
                    const float* __restrict__ t0, const float* __restrict__ t1,
                    const float* __restrict__ t2, const float* __restrict__ t3,
                    const float* __restrict__ w0, const float* __restrict__ b0,
                    const float* __restrict__ w1, const float* __restrict__ b1,
                    const float* __restrict__ w2, const float* __restrict__ b2,
                    const float* __restrict__ w3, const float* __restrict__ b3,
                    const float* __restrict__ wout, const float* __restrict__ bout,
                    float* __restrict__ out, int n_pts) {
    int n = blockIdx.x * blockDim.x + threadIdx.x;
    if (n >= n_pts) return;

    const float2 xv = *reinterpret_cast<const float2*>(x + (size_t)2 * n);
    float sy = 1.0f / (1.0f + expf(-xv.x));  // s[:,0] -> iy
    float sx = 1.0f / (1.0f + expf(-xv.y));  // s[:,1] -> ix

    float feats[16];
    sample_level<ILV, 64 >(ILV ? t0 : d0, sy, sx, feats + 0);
    sample_level<ILV, 128>(ILV ? t1 : d1, sy, sx, feats + 4);
    sample_level<ILV, 256>(ILV ? t2 : d2, sy, sx, feats + 8);
    sample_level<ILV, 512>(ILV ? t3 : d3, sy, sx, feats + 12);

    float ha[64], hb[64];

    // layer 0: 16 -> 64
#pragma unroll
    for (int j = 0; j < 64; ++j) ha[j] = b0[j];
#pragma unroll
    for (int k = 0; k < 16; ++k) {
        float fk = feats[k];
#pragma unroll
        for (int j = 0; j < 64; ++j) ha[j] = fmaf(fk, w0[k * 64 + j], ha[j]);
    }
#pragma unroll
    for (int j = 0; j < 64; ++j) ha[j] = fmaxf(ha[j], 0.f);

    LAYER64(ha, hb, w1, b1);   // layer 1
    LAYER64(hb, ha, w2, b2);   // layer 2
    LAYER64(ha, hb, w3, b3);   // layer 3

    // output: 64 -> 4
    float o0 = bout[0], o1 = bout[1], o2 = bout[2], o3 = bout[3];
#pragma unroll
    for (int k = 0; k < 64; ++k) {
        float fk = hb[k];
        o0 = fmaf(fk, wout[k * 4 + 0], o0);
        o1 = fmaf(fk, wout[k * 4 + 1], o1);
        o2 = fmaf(fk, wout[k * 4 + 2], o2);
        o3 = fmaf(fk, wout[k * 4 + 3], o3);
    }
    float4 ov = make_float4(o0, o1, o2, o3);
    *reinterpret_cast<float4*>(out + (size_t)n * 4) = ov;
}

extern "C" void kernel_launch(void* const* d_in, const int* in_sizes, int n_in,
                              void* d_out, int out_size, void* d_ws, size_t ws_size,
                              hipStream_t stream) {
    const float* x  = (const float*)d_in[0];
    const float* d0 = (const float*)d_in[1];
    const float* d1 = (const float*)d_in[2];
    const float* d2 = (const float*)d_in[3];
    const float* d3 = (const float*)d_in[4];
    const float* w0 = (const float*)d_in[5];
    const float* b0 = (const float*)d_in[6];
    const float* w1 = (const float*)d_in[7];
    const float* b1 = (const float*)d_in[8];
    const float* w2 = (const float*)d_in[9];
    const float* b2 = (const float*)d_in[10];
    const float* w3 = (const float*)d_in[11];
    const float* b3 = (const float*)d_in[12];
    const float* wout = (const float*)d_in[13];
    const float* bout = (const float*)d_in[14];
    float* out = (float*)d_out;

    const int N = in_sizes[0] / 2;  // (N,2)

    // interleaved texel tables in ws: float counts per level (R*R*4)
    const size_t f0 = 0;
    const size_t f1 = f0 + (size_t)64 * 64 * 4;      // 16384
    const size_t f2 = f1 + (size_t)128 * 128 * 4;    // 81920
    const size_t f3 = f2 + (size_t)256 * 256 * 4;    // 344064
    const size_t ftot = f3 + (size_t)512 * 512 * 4;  // 1392640 floats
    const bool ilv = ws_size >= ftot * sizeof(float);

    float* ws = (float*)d_ws;
    float* t0 = ws + f0;
    float* t1 = ws + f1;
    float* t2 = ws + f2;
    float* t3 = ws + f3;

    if (ilv) {
        const float* ins[4] = {d0, d1, d2, d3};
        float* outs[4] = {t0, t1, t2, t3};
        const int rrs[4] = {64 * 64, 128 * 128, 256 * 256, 512 * 512};
        for (int l = 0; l < 4; ++l) {
            int total = rrs[l] * 4;
            int blocks = (total + 255) / 256;
            hipLaunchKernelGGL(interleave_kernel, dim3(blocks), dim3(256), 0, stream,
                               ins[l], outs[l], rrs[l]);
        }
    }

    int blocks = (N + 255) / 256;
    if (ilv) {
        hipLaunchKernelGGL((mrv_mlp_kernel<true>), dim3(blocks), dim3(256), 0, stream,
                           x, d0, d1, d2, d3, t0, t1, t2, t3,
                           w0, b0, w1, b1, w2, b2, w3, b3, wout, bout, out, N);
    } else {
        hipLaunchKernelGGL((mrv_mlp_kernel<false>), dim3(blocks), dim3(256), 0, stream,
                           x, d0, d1, d2, d3, t0, t1, t2, t3,
                           w0, b0, w1, b1, w2, b2, w3, b3, wout, bout, out, N);
    }
}

// Round 3
// 219.738 us; speedup vs baseline: 4.9350x; 4.9350x over previous
//
#include <hip/hip_runtime.h>

#define A_COEF (-0.75f)

typedef unsigned int u32;
using bf16x8 = __attribute__((ext_vector_type(8))) short;
using f32x16 = __attribute__((ext_vector_type(16))) float;

__device__ __forceinline__ float cc1(float t) {
    return ((A_COEF + 2.0f) * t - (A_COEF + 3.0f)) * t * t + 1.0f;
}
__device__ __forceinline__ float cc2(float t) {
    return ((A_COEF * t - 5.0f * A_COEF) * t + 8.0f * A_COEF) * t - 4.0f * A_COEF;
}

// ---------------- prep kernel 1: channel-interleave tables ----------------
// data[c][y][x] (C=4, RxR) -> tex[(y*R+x)*4 + c]
__global__ void interleave_kernel(const float* __restrict__ in, float* __restrict__ out, int RR) {
    int i = blockIdx.x * blockDim.x + threadIdx.x;
    if (i >= RR * 4) return;
    int c = i & 3;
    int t = i >> 2;
    out[i] = in[c * RR + t];
}

// ---------------- prep kernel 2: weight fragments (hi/lo bf16) ----------------
// Frag layout: frag[f][lane][elem] bf16, f*512 + lane*8 + elem.
// A-operand = W^T: element(m,k) = W[k][m]; m = mt*32 + (lane&31),
// k = ks*16 + 8*(elem>>2) + 4*(lane>>5) + (elem&3)   [CDNA4 doubled-K = two K-halves]
// f ids: L0: 0 + mt*2 + hl (ks=0). L1..L3: 4+16*(L-1) + (mt*4+ks)*2 + hl. wout: 52 + ks*2 + hl.
__global__ void frag_pack_kernel(const float* __restrict__ w0, const float* __restrict__ w1,
                                 const float* __restrict__ w2, const float* __restrict__ w3,
                                 const float* __restrict__ wout, unsigned short* __restrict__ fr) {
    int t = blockIdx.x * blockDim.x + threadIdx.x;
    if (t >= 60 * 64) return;
    int f = t >> 6, lane = t & 63;
    int layer, mt, ks, hl;
    if (f < 4)       { layer = 0; mt = f >> 1; ks = 0; hl = f & 1; }
    else if (f < 52) { int r = f - 4; layer = 1 + r / 16; r %= 16; mt = r >> 3; ks = (r >> 1) & 3; hl = r & 1; }
    else             { int r = f - 52; layer = 4; mt = 0; ks = r >> 1; hl = r & 1; }

    const float* W; int Mdim, Kdim;
    if (layer == 0)      { W = w0;   Mdim = 64; Kdim = 16; }
    else if (layer == 1) { W = w1;   Mdim = 64; Kdim = 64; }
    else if (layer == 2) { W = w2;   Mdim = 64; Kdim = 64; }
    else if (layer == 3) { W = w3;   Mdim = 64; Kdim = 64; }
    else                 { W = wout; Mdim = 4;  Kdim = 64; }

    int m = mt * 32 + (lane & 31);
    int g = lane >> 5;
    unsigned short o[8];
#pragma unroll
    for (int jj = 0; jj < 8; ++jj) {
        int k = ks * 16 + 8 * (jj >> 2) + 4 * g + (jj & 3);
        float v = (m < Mdim && k < Kdim) ? W[k * Mdim + m] : 0.0f;
        u32 u = __float_as_uint(v);
        u32 hi = (u + 0x7FFFu + ((u >> 16) & 1u)) >> 16;  // RNE to bf16
        if (hl == 0) {
            o[jj] = (unsigned short)hi;
        } else {
            float vh = __uint_as_float(hi << 16);
            float lo = v - vh;
            u32 ul = __float_as_uint(lo);
            u32 lb = (ul + 0x7FFFu + ((ul >> 16) & 1u)) >> 16;
            o[jj] = (unsigned short)lb;
        }
    }
    u32 a = (u32)o[0] | ((u32)o[1] << 16);
    u32 b = (u32)o[2] | ((u32)o[3] << 16);
    u32 c = (u32)o[4] | ((u32)o[5] << 16);
    u32 d = (u32)o[6] | ((u32)o[7] << 16);
    uint4 val; val.x = a; val.y = b; val.z = c; val.w = d;
    *(uint4*)(fr + (size_t)f * 512 + lane * 8) = val;
}

// ---------------- sampling (runtime R, interleaved float4 texels) ----------------
__device__ __forceinline__ float4 sample_lvl(const float4* __restrict__ tb, int R, float sy, float sx) {
    float RM1f = (float)(R - 1);
    float fy = sy * RM1f, fx = sx * RM1f;
    float y0f = floorf(fy), x0f = floorf(fx);
    float ty = fy - y0f, tx = fx - x0f;
    int y0 = (int)y0f, x0 = (int)x0f;
    float wxa[4] = {cc2(tx + 1.0f), cc1(tx), cc1(1.0f - tx), cc2(2.0f - tx)};
    float wya[4] = {cc2(ty + 1.0f), cc1(ty), cc1(1.0f - ty), cc2(2.0f - ty)};
    int xs[4], ys[4];
#pragma unroll
    for (int j = 0; j < 4; ++j) {
        xs[j] = min(max(x0 - 1 + j, 0), R - 1);
        ys[j] = min(max(y0 - 1 + j, 0), R - 1);
    }
    float a0 = 0.f, a1 = 0.f, a2 = 0.f, a3 = 0.f;
#pragma unroll
    for (int i = 0; i < 4; ++i) {
        const float4* rp = tb + (size_t)ys[i] * R;
        float r0 = 0.f, r1 = 0.f, r2 = 0.f, r3 = 0.f;
#pragma unroll
        for (int j = 0; j < 4; ++j) {
            float4 v = rp[xs[j]];
            r0 = fmaf(wxa[j], v.x, r0);
            r1 = fmaf(wxa[j], v.y, r1);
            r2 = fmaf(wxa[j], v.z, r2);
            r3 = fmaf(wxa[j], v.w, r3);
        }
        a0 = fmaf(wya[i], r0, a0);
        a1 = fmaf(wya[i], r1, a1);
        a2 = fmaf(wya[i], r2, a2);
        a3 = fmaf(wya[i], r3, a3);
    }
    return make_float4(a0, a1, a2, a3);
}

// ---------------- MFMA helpers ----------------
__device__ __forceinline__ bf16x8 pack8(const u32 b[4]) {
    union { u32 u[4]; bf16x8 v; } t;
    t.u[0] = b[0]; t.u[1] = b[1]; t.u[2] = b[2]; t.u[3] = b[3];
    return t.v;
}

template <int NKS>
__device__ __forceinline__ void mlp_layer(const unsigned short* __restrict__ fl, int fbase, int lane,
                                          const u32 (&Bhi)[4][4], const u32 (&Blo)[4][4],
                                          const float* __restrict__ bias64, f32x16* __restrict__ acc) {
    int g = lane >> 5;
#pragma unroll
    for (int mt = 0; mt < 2; ++mt) {
        f32x16 a;
        const float* bb = bias64 + 4 * g + 32 * mt;
#pragma unroll
        for (int q = 0; q < 4; ++q) {
            float4 b4 = *(const float4*)(bb + 8 * q);
            a[4 * q + 0] = b4.x; a[4 * q + 1] = b4.y; a[4 * q + 2] = b4.z; a[4 * q + 3] = b4.w;
        }
#pragma unroll
        for (int ks = 0; ks < NKS; ++ks) {
            const bf16x8 ahi = *(const bf16x8*)(fl + ((size_t)(fbase + (mt * NKS + ks) * 2 + 0)) * 512 + lane * 8);
            const bf16x8 alo = *(const bf16x8*)(fl + ((size_t)(fbase + (mt * NKS + ks) * 2 + 1)) * 512 + lane * 8);
            bf16x8 bhi = pack8(Bhi[ks]);
            bf16x8 blo = pack8(Blo[ks]);
            a = __builtin_amdgcn_mfma_f32_32x32x16_bf16(ahi, bhi, a, 0, 0, 0);
            a = __builtin_amdgcn_mfma_f32_32x32x16_bf16(ahi, blo, a, 0, 0, 0);
            a = __builtin_amdgcn_mfma_f32_32x32x16_bf16(alo, bhi, a, 0, 0, 0);
        }
        acc[mt] = a;
    }
}

// acc -> relu -> hi/lo bf16 -> next layer's B-frags. FULLY LANE-LOCAL:
// C layout: point=lane&31, n=(r&3)+8*(r>>2)+4g+32mt
// B layout: point=lane&31, k=16ks+8*(e>>2)+4g+(e&3)
// Both carry the same +4g term, so needed k-set == held n-set.
// Word w of B[ks] = cvt_pk(acc[ks>>1][r0], acc[ks>>1][r0+1]), r0=8(ks&1)+4(w>>1)+2(w&1).
__device__ __forceinline__ void acc_to_B(const f32x16* __restrict__ acc, u32 (&Bhi)[4][4], u32 (&Blo)[4][4]) {
#pragma unroll
    for (int ks = 0; ks < 4; ++ks) {
#pragma unroll
        for (int w = 0; w < 4; ++w) {
            const int r0 = 8 * (ks & 1) + 4 * (w >> 1) + 2 * (w & 1);
            float va = fmaxf(acc[ks >> 1][r0], 0.f);
            float vb = fmaxf(acc[ks >> 1][r0 + 1], 0.f);
            u32 qh;
            asm("v_cvt_pk_bf16_f32 %0, %1, %2" : "=v"(qh) : "v"(va), "v"(vb));
            float la = va - __uint_as_float(qh << 16);
            float lb = vb - __uint_as_float(qh & 0xFFFF0000u);
            u32 ql;
            asm("v_cvt_pk_bf16_f32 %0, %1, %2" : "=v"(ql) : "v"(la), "v"(lb));
            Bhi[ks][w] = qh;
            Blo[ks][w] = ql;
        }
    }
}

// ---------------- main kernel ----------------
__global__ __launch_bounds__(512, 4)
void mrv_mfma_kernel(const float* __restrict__ x,
                     const float* __restrict__ tex_f,       // interleaved tables (float4 texels)
                     const unsigned short* __restrict__ frg,// packed weight frags in ws
                     const float* __restrict__ b0, const float* __restrict__ b1,
                     const float* __restrict__ b2, const float* __restrict__ b3,
                     const float* __restrict__ bout,
                     float* __restrict__ out, int N, int nbatch) {
    __shared__ __attribute__((aligned(16))) unsigned short frag_lds[60 * 512];
    __shared__ __attribute__((aligned(16))) float bias_lds[4 * 64];

    // stage frags (61440 B) + biases into LDS
    {
        const uint4* src = (const uint4*)frg;
        uint4* dst = (uint4*)frag_lds;
#pragma unroll
        for (int i = 0; i < 8; ++i) {
            int idx = threadIdx.x + i * 512;
            if (idx < 3840) dst[idx] = src[idx];
        }
        if (threadIdx.x < 256) {
            int L = threadIdx.x >> 6, i = threadIdx.x & 63;
            const float* bp = (L == 0) ? b0 : (L == 1) ? b1 : (L == 2) ? b2 : b3;
            bias_lds[threadIdx.x] = bp[i];
        }
    }
    __syncthreads();

    const int lane = threadIdx.x & 63;
    const int wid = threadIdx.x >> 6;
    const int g = lane >> 5;
    const float4 bo = *(const float4*)bout;
    const float4* tex = (const float4*)tex_f;

    for (int it = 0;; ++it) {
        int batch = blockIdx.x + it * gridDim.x;
        if (batch >= nbatch) break;
        int pbase = batch * 256 + wid * 32;
        int p = pbase + (lane & 31);
        int pc = min(p, N - 1);

        float2 xv = ((const float2*)x)[pc];
        float sy = 1.0f / (1.0f + expf(-xv.x));
        float sx = 1.0f / (1.0f + expf(-xv.y));

        // B-frag k-set of half-wave g for layer 0 is {4g..4g+3, 8+4g..8+4g+3}
        // = channels of level g (k=4g+c) and level g+2 (k=8+4g+c).
        float f[8];
#pragma unroll
        for (int lv = 0; lv < 2; ++lv) {
            int lvl = g + 2 * lv;
            int off4 = (lvl == 0) ? 0 : (lvl == 1) ? 4096 : (lvl == 2) ? 20480 : 86016;
            int R = 64 << lvl;
            float4 s = sample_lvl(tex + off4, R, sy, sx);
            f[4 * lv + 0] = s.x; f[4 * lv + 1] = s.y; f[4 * lv + 2] = s.z; f[4 * lv + 3] = s.w;
        }

        // pack features -> B[0] words: w0={f0,f1} w1={f2,f3} w2={f4,f5} w3={f6,f7}
        u32 Bhi[4][4], Blo[4][4];
#pragma unroll
        for (int w = 0; w < 4; ++w) {
            float a = f[2 * w], b = f[2 * w + 1];
            u32 qh;
            asm("v_cvt_pk_bf16_f32 %0, %1, %2" : "=v"(qh) : "v"(a), "v"(b));
            float la = a - __uint_as_float(qh << 16);
            float lb = b - __uint_as_float(qh & 0xFFFF0000u);
            u32 ql;
            asm("v_cvt_pk_bf16_f32 %0, %1, %2" : "=v"(ql) : "v"(la), "v"(lb));
            Bhi[0][w] = qh; Blo[0][w] = ql;
        }

        f32x16 acc[2];
        mlp_layer<1>(frag_lds, 0,  lane, Bhi, Blo, bias_lds + 0,   acc);
        acc_to_B(acc, Bhi, Blo);
        mlp_layer<4>(frag_lds, 4,  lane, Bhi, Blo, bias_lds + 64,  acc);
        acc_to_B(acc, Bhi, Blo);
        mlp_layer<4>(frag_lds, 20, lane, Bhi, Blo, bias_lds + 128, acc);
        acc_to_B(acc, Bhi, Blo);
        mlp_layer<4>(frag_lds, 36, lane, Bhi, Blo, bias_lds + 192, acc);
        acc_to_B(acc, Bhi, Blo);

        // output layer: M=4 (padded to 32), single m-tile
        f32x16 ao;
#pragma unroll
        for (int r = 0; r < 16; ++r)
            ao[r] = (g == 0 && r < 4) ? ((r == 0) ? bo.x : (r == 1) ? bo.y : (r == 2) ? bo.z : bo.w) : 0.0f;
#pragma unroll
        for (int ks = 0; ks < 4; ++ks) {
            const bf16x8 ahi = *(const bf16x8*)(frag_lds + ((size_t)(52 + ks * 2 + 0)) * 512 + lane * 8);
            const bf16x8 alo = *(const bf16x8*)(frag_lds + ((size_t)(52 + ks * 2 + 1)) * 512 + lane * 8);
            bf16x8 bhi = pack8(Bhi[ks]);
            bf16x8 blo = pack8(Blo[ks]);
            ao = __builtin_amdgcn_mfma_f32_32x32x16_bf16(ahi, bhi, ao, 0, 0, 0);
            ao = __builtin_amdgcn_mfma_f32_32x32x16_bf16(ahi, blo, ao, 0, 0, 0);
            ao = __builtin_amdgcn_mfma_f32_32x32x16_bf16(alo, bhi, ao, 0, 0, 0);
        }
        if (g == 0 && p < N)
            ((float4*)out)[p] = make_float4(ao[0], ao[1], ao[2], ao[3]);
    }
}

// ---------------- fallback (direct-layout f32 VALU, round-1 path) ----------------
__global__ __launch_bounds__(256)
void mrv_fallback_kernel(const float* __restrict__ x,
                         const float* __restrict__ d0, const float* __restrict__ d1,
                         const float* __restrict__ d2, const float* __restrict__ d3,
                         const float* __restrict__ w0, const float* __restrict__ b0,
                         const float* __restrict__ w1, const float* __restrict__ b1,
                         const float* __restrict__ w2, const float* __restrict__ b2,
                         const float* __restrict__ w3, const float* __restrict__ b3,
                         const float* __restrict__ wout, const float* __restrict__ bout,
                         float* __restrict__ out, int n_pts) {
    int n = blockIdx.x * blockDim.x + threadIdx.x;
    if (n >= n_pts) return;
    const float2 xv = *reinterpret_cast<const float2*>(x + (size_t)2 * n);
    float sy = 1.0f / (1.0f + expf(-xv.x));
    float sx = 1.0f / (1.0f + expf(-xv.y));
    float feats[16];
    const float* ds[4] = {d0, d1, d2, d3};
#pragma unroll
    for (int l = 0; l < 4; ++l) {
        int R = 64 << l;
        float RM1f = (float)(R - 1);
        float fy = sy * RM1f, fx = sx * RM1f;
        float y0f = floorf(fy), x0f = floorf(fx);
        float ty = fy - y0f, tx = fx - x0f;
        int y0 = (int)y0f, x0 = (int)x0f;
        float wxa[4] = {cc2(tx + 1.0f), cc1(tx), cc1(1.0f - tx), cc2(2.0f - tx)};
        float wya[4] = {cc2(ty + 1.0f), cc1(ty), cc1(1.0f - ty), cc2(2.0f - ty)};
        int xs[4], ys[4];
#pragma unroll
        for (int j = 0; j < 4; ++j) {
            xs[j] = min(max(x0 - 1 + j, 0), R - 1);
            ys[j] = min(max(y0 - 1 + j, 0), R - 1);
        }
#pragma unroll
        for (int c = 0; c < 4; ++c) {
            const float* cp = ds[l] + (size_t)c * R * R;
            float ac = 0.f;
#pragma unroll
            for (int i = 0; i < 4; ++i) {
                const float* rowp = cp + (size_t)(ys[i] * R);
                float r = 0.f;
#pragma unroll
                for (int j = 0; j < 4; ++j) r = fmaf(wxa[j], rowp[xs[j]], r);
                ac = fmaf(wya[i], r, ac);
            }
            feats[l * 4 + c] = ac;
        }
    }
    float ha[64], hb[64];
#pragma unroll
    for (int j = 0; j < 64; ++j) ha[j] = b0[j];
#pragma unroll
    for (int k = 0; k < 16; ++k) {
        float fk = feats[k];
#pragma unroll
        for (int j = 0; j < 64; ++j) ha[j] = fmaf(fk, w0[k * 64 + j], ha[j]);
    }
#pragma unroll
    for (int j = 0; j < 64; ++j) ha[j] = fmaxf(ha[j], 0.f);
#define LYR(IN, OUT, W, B)                                                  \
    _Pragma("unroll") for (int j = 0; j < 64; ++j) OUT[j] = (B)[j];         \
    _Pragma("unroll") for (int k = 0; k < 64; ++k) {                        \
        float fk = IN[k];                                                   \
        _Pragma("unroll") for (int j = 0; j < 64; ++j)                      \
            OUT[j] = fmaf(fk, (W)[k * 64 + j], OUT[j]);                     \
    }                                                                       \
    _Pragma("unroll") for (int j = 0; j < 64; ++j) OUT[j] = fmaxf(OUT[j], 0.f);
    LYR(ha, hb, w1, b1)
    LYR(hb, ha, w2, b2)
    LYR(ha, hb, w3, b3)
    float o0 = bout[0], o1 = bout[1], o2 = bout[2], o3 = bout[3];
#pragma unroll
    for (int k = 0; k < 64; ++k) {
        float fk = hb[k];
        o0 = fmaf(fk, wout[k * 4 + 0], o0);
        o1 = fmaf(fk, wout[k * 4 + 1], o1);
        o2 = fmaf(fk, wout[k * 4 + 2], o2);
        o3 = fmaf(fk, wout[k * 4 + 3], o3);
    }
    *reinterpret_cast<float4*>(out + (size_t)n * 4) = make_float4(o0, o1, o2, o3);
}

extern "C" void kernel_launch(void* const* d_in, const int* in_sizes, int n_in,
                              void* d_out, int out_size, void* d_ws, size_t ws_size,
                              hipStream_t stream) {
    const float* x  = (const float*)d_in[0];
    const float* d0 = (const float*)d_in[1];
    const float* d1 = (const float*)d_in[2];
    const float* d2 = (const float*)d_in[3];
    const float* d3 = (const float*)d_in[4];
    const float* w0 = (const float*)d_in[5];
    const float* b0 = (const float*)d_in[6];
    const float* w1 = (const float*)d_in[7];
    const float* b1 = (const float*)d_in[8];
    const float* w2 = (const float*)d_in[9];
    const float* b2 = (const float*)d_in[10];
    const float* w3 = (const float*)d_in[11];
    const float* b3 = (const float*)d_in[12];
    const float* wout = (const float*)d_in[13];
    const float* bout = (const float*)d_in[14];
    float* out = (float*)d_out;

    const int N = in_sizes[0] / 2;

    const size_t f0 = 0;
    const size_t f1 = f0 + (size_t)64 * 64 * 4;
    const size_t f2 = f1 + (size_t)128 * 128 * 4;
    const size_t f3 = f2 + (size_t)256 * 256 * 4;
    const size_t ftot = f3 + (size_t)512 * 512 * 4;         // 1,392,640 floats
    const size_t need = ftot * sizeof(float) + 60 * 512 * sizeof(unsigned short);

    if (ws_size < need) {
        int blocks = (N + 255) / 256;
        hipLaunchKernelGGL(mrv_fallback_kernel, dim3(blocks), dim3(256), 0, stream,
                           x, d0, d1, d2, d3, w0, b0, w1, b1, w2, b2, w3, b3, wout, bout, out, N);
        return;
    }

    float* ws = (float*)d_ws;
    unsigned short* frg = (unsigned short*)(ws + ftot);

    const float* ins[4] = {d0, d1, d2, d3};
    float* outs[4] = {ws + f0, ws + f1, ws + f2, ws + f3};
    const int rrs[4] = {64 * 64, 128 * 128, 256 * 256, 512 * 512};
    for (int l = 0; l < 4; ++l) {
        int total = rrs[l] * 4;
        hipLaunchKernelGGL(interleave_kernel, dim3((total + 255) / 256), dim3(256), 0, stream,
                           ins[l], outs[l], rrs[l]);
    }
    hipLaunchKernelGGL(frag_pack_kernel, dim3(15), dim3(256), 0, stream,
                       w0, w1, w2, w3, wout, frg);

    const int nbatch = (N + 255) / 256;
    hipLaunchKernelGGL(mrv_mfma_kernel, dim3(512), dim3(512), 0, stream,
                       x, ws, frg, b0, b1, b2, b3, bout, out, N, nbatch);
}